// Round 3
// baseline (889.053 us; speedup 1.0000x reference)
//
#include <hip/hip_runtime.h>
#include <hip/hip_bf16.h>

// Problem constants (fixed by setup_inputs)
#define BB   32      // batch
#define TT   4096    // seq len
#define CTXD 1024    // encoder hidden (K of the big GEMM)
#define HH   256     // attention hidden (N of the big GEMM)
#define DH   512     // decoder hidden
#define BT   64      // t-rows per block
#define NTILES (TT/BT)  // 64 tiles per batch
#define BK   32      // K-chunk staged per iteration
#define NKT  (CTXD/BK)  // 32 iterations
#define LDA  1032    // As row stride in bf16: 2064 B = 516 dw == 4 mod 32 banks
// dynamic LDS: As 64*1032*2 = 132096 + epart 1024 + pbuf 256 = 133376 B
#define SMEM_BYTES (BT*LDA*2 + 4*BT*4 + BT*4)

typedef __attribute__((ext_vector_type(8))) short bf16x8;
typedef __attribute__((ext_vector_type(4))) float f32x4;

static __device__ __forceinline__ unsigned short f2bf(float f) {
    unsigned int u = __float_as_uint(f);
    u += 0x7FFF + ((u >> 16) & 1);   // round-to-nearest-even
    return (unsigned short)(u >> 16);
}
static __device__ __forceinline__ unsigned pack2(float x, float y) {
    return (unsigned)f2bf(x) | ((unsigned)f2bf(y) << 16);
}
static __device__ __forceinline__ float bf2f(unsigned short u) {
    return __uint_as_float((unsigned)u << 16);
}

// ---- prep: U_w fp32 -> bf16 (row-major [H][CTX]) ----
__global__ void uconv_kernel(const float* __restrict__ Uw, unsigned short* __restrict__ Ub) {
    int idx = blockIdx.x * blockDim.x + threadIdx.x;
    float4 u4 = ((const float4*)Uw)[idx];
    ushort4 o;
    o.x = f2bf(u4.x); o.y = f2bf(u4.y); o.z = f2bf(u4.z); o.w = f2bf(u4.w);
    ((ushort4*)Ub)[idx] = o;
}

// ---- prep: bias[b,h] = prev[b,:]·W_w[h,:] + W_b[h] + U_b[h] (full fp32) ----
__global__ void bias_kernel(const float* __restrict__ prev, const float* __restrict__ Ww,
                            const float* __restrict__ Wb, const float* __restrict__ Ubias,
                            float* __restrict__ bias) {
    __shared__ float ps[DH];
    int b = blockIdx.x, h = threadIdx.x;
    if (h < DH / 4) ((float4*)ps)[h] = ((const float4*)(prev + (size_t)b * DH))[h];
    __syncthreads();
    float acc = Wb[h] + Ubias[h];
    const float4* wr = (const float4*)(Ww + (size_t)h * DH);
    #pragma unroll 4
    for (int d = 0; d < DH / 4; ++d) {
        float4 w4 = wr[d];
        float4 p4 = ((const float4*)ps)[d];
        acc += w4.x * p4.x + w4.y * p4.y + w4.z * p4.z + w4.w * p4.w;
    }
    bias[b * HH + h] = acc;
}

// ---- main: single-pass over enc. Persistent full-row bf16 A-tile in LDS.
//      B-fragments fed straight from global (U is L2-resident) -> no Us, ONE
//      barrier per kt. A-chunk loads pipelined 3 deep via register rotation. ----
__global__ __launch_bounds__(256, 1)
void attn_main(const float* __restrict__ enc, const unsigned short* __restrict__ Ub,
               const float* __restrict__ bias, const float* __restrict__ v,
               float* __restrict__ partO, float* __restrict__ partM,
               float* __restrict__ partL) {
    extern __shared__ __align__(16) char smem[];
    unsigned short* As = (unsigned short*)smem;            // 64 x LDA (persistent bf16 tile)
    float* epart = (float*)(smem + BT * LDA * 2);          // [4][64]
    float* pbuf  = epart + 4 * BT;                         // [64]

    const int tid  = threadIdx.x;
    const int lane = tid & 63;
    const int w    = tid >> 6;         // wave 0..3 -> N columns [64w, 64w+64)
    const int quad = lane >> 4;
    const int l15  = lane & 15;
    const int b    = blockIdx.x & 31;
    const int tile = blockIdx.x >> 5;
    const int t0   = tile * BT;
    const int pi   = b * NTILES + tile;

    // A staging map: 4 threads per row, 8 consecutive floats (32 B) each
    const int srow = tid >> 2;     // 0..63
    const int sg   = tid & 3;      // 8-float granule within the 32-col chunk
    const float* gA = enc + ((size_t)b * TT + t0 + srow) * CTXD + sg * 8;

    // B-fragment global bases (per ni): row h, k-window quad*8
    const unsigned short* gB0 = Ub + (size_t)(w * 64 +  0 + l15) * CTXD + quad * 8;
    const unsigned short* gB1 = Ub + (size_t)(w * 64 + 16 + l15) * CTXD + quad * 8;
    const unsigned short* gB2 = Ub + (size_t)(w * 64 + 32 + l15) * CTXD + quad * 8;
    const unsigned short* gB3 = Ub + (size_t)(w * 64 + 48 + l15) * CTXD + quad * 8;

    f32x4 acc[4][4];
    #pragma unroll
    for (int mi = 0; mi < 4; ++mi)
        #pragma unroll
        for (int ni = 0; ni < 4; ++ni) acc[mi][ni] = (f32x4){0.f, 0.f, 0.f, 0.f};

    // prologue: chunk 0 -> LDS; chunks 1,2 in flight; B-frags for kt=0 in flight
    float4 c0a = *(const float4*)(gA);
    float4 c0b = *(const float4*)(gA + 4);
    float4 p0a = *(const float4*)(gA + BK);
    float4 p0b = *(const float4*)(gA + BK + 4);
    float4 p1a = *(const float4*)(gA + 2 * BK);
    float4 p1b = *(const float4*)(gA + 2 * BK + 4);
    bf16x8 bcur0 = *(const bf16x8*)(gB0);
    bf16x8 bcur1 = *(const bf16x8*)(gB1);
    bf16x8 bcur2 = *(const bf16x8*)(gB2);
    bf16x8 bcur3 = *(const bf16x8*)(gB3);
    {
        uint4 pa;
        pa.x = pack2(c0a.x, c0a.y); pa.y = pack2(c0a.z, c0a.w);
        pa.z = pack2(c0b.x, c0b.y); pa.w = pack2(c0b.z, c0b.w);
        *(uint4*)&As[srow * LDA + sg * 8] = pa;
    }
    __syncthreads();

    for (int kt = 0; kt < NKT; ++kt) {
        // issue A loads for chunk kt+3 (clamped; tail repeats are harmless)
        int ln = kt + 3 < NKT ? kt + 3 : NKT - 1;
        float4 n0 = *(const float4*)(gA + ln * BK);
        float4 n1 = *(const float4*)(gA + ln * BK + 4);
        // issue B-frag loads for kt+1 (clamped)
        int bn = kt + 1 < NKT ? kt + 1 : NKT - 1;
        bf16x8 bn0 = *(const bf16x8*)(gB0 + bn * BK);
        bf16x8 bn1 = *(const bf16x8*)(gB1 + bn * BK);
        bf16x8 bn2 = *(const bf16x8*)(gB2 + bn * BK);
        bf16x8 bn3 = *(const bf16x8*)(gB3 + bn * BK);

        // stage chunk kt+1 (disjoint from chunk kt being read -> no hazard)
        if (kt + 1 < NKT) {
            uint4 pa;
            pa.x = pack2(p0a.x, p0a.y); pa.y = pack2(p0a.z, p0a.w);
            pa.z = pack2(p0b.x, p0b.y); pa.w = pack2(p0b.z, p0b.w);
            *(uint4*)&As[srow * LDA + (kt + 1) * BK + sg * 8] = pa;
        }

        // MFMA on chunk kt (published by last iteration's barrier)
        bf16x8 af[4];
        #pragma unroll
        for (int mi = 0; mi < 4; ++mi)
            af[mi] = *(const bf16x8*)&As[(mi * 16 + l15) * LDA + kt * BK + quad * 8];
        #pragma unroll
        for (int mi = 0; mi < 4; ++mi) {
            acc[mi][0] = __builtin_amdgcn_mfma_f32_16x16x32_bf16(af[mi], bcur0, acc[mi][0], 0, 0, 0);
            acc[mi][1] = __builtin_amdgcn_mfma_f32_16x16x32_bf16(af[mi], bcur1, acc[mi][1], 0, 0, 0);
            acc[mi][2] = __builtin_amdgcn_mfma_f32_16x16x32_bf16(af[mi], bcur2, acc[mi][2], 0, 0, 0);
            acc[mi][3] = __builtin_amdgcn_mfma_f32_16x16x32_bf16(af[mi], bcur3, acc[mi][3], 0, 0, 0);
        }
        __syncthreads();   // publish chunk kt+1

        // rotate pipeline registers
        p0a = p1a; p0b = p1b; p1a = n0; p1b = n1;
        bcur0 = bn0; bcur1 = bn1; bcur2 = bn2; bcur3 = bn3;
    }

    // epilogue: energy[t] = sum_h relu(S[t,h] + bias[b,h]) * v[h]
    float vv[4], bb[4];
    #pragma unroll
    for (int ni = 0; ni < 4; ++ni) {
        int h = w * 64 + ni * 16 + l15;
        vv[ni] = v[h];
        bb[ni] = bias[b * HH + h];
    }
    #pragma unroll
    for (int mi = 0; mi < 4; ++mi) {
        #pragma unroll
        for (int r = 0; r < 4; ++r) {
            float e = 0.f;
            #pragma unroll
            for (int ni = 0; ni < 4; ++ni) {
                float x = acc[mi][ni][r] + bb[ni];
                e += fmaxf(x, 0.f) * vv[ni];
            }
            e += __shfl_xor(e, 1);
            e += __shfl_xor(e, 2);
            e += __shfl_xor(e, 4);
            e += __shfl_xor(e, 8);
            if (l15 == 0) epart[w * BT + mi * 16 + quad * 4 + r] = e;
        }
    }
    __syncthreads();

    // block softmax (local m,l) by wave 0
    if (tid < 64) {
        float e = epart[0 * BT + tid] + epart[1 * BT + tid] + epart[2 * BT + tid] + epart[3 * BT + tid];
        float m = e;
        #pragma unroll
        for (int off = 32; off; off >>= 1) m = fmaxf(m, __shfl_xor(m, off));
        float p = __expf(e - m);
        float l = p;
        #pragma unroll
        for (int off = 32; off; off >>= 1) l += __shfl_xor(l, off);
        pbuf[tid] = p;
        if (tid == 0) { partM[pi] = m; partL[pi] = l; }
    }
    __syncthreads();

    // phase 3: partial context from the LDS bf16 tile — no HBM re-read
    const int c4 = tid * 4;
    float o0 = 0.f, o1 = 0.f, o2 = 0.f, o3 = 0.f;
    #pragma unroll 8
    for (int t = 0; t < BT; ++t) {
        float p = pbuf[t];
        ushort4 e4 = *(const ushort4*)&As[t * LDA + c4];
        o0 += p * bf2f(e4.x);
        o1 += p * bf2f(e4.y);
        o2 += p * bf2f(e4.z);
        o3 += p * bf2f(e4.w);
    }
    float4 r4; r4.x = o0; r4.y = o1; r4.z = o2; r4.w = o3;
    *(float4*)(partO + (size_t)pi * CTXD + c4) = r4;
}

// ---- combine: per batch merge 64 (o,m,l) partials ----
__global__ void combine_kernel(const float* __restrict__ partO, const float* __restrict__ partM,
                               const float* __restrict__ partL, float* __restrict__ out) {
    __shared__ float sc[NTILES];
    __shared__ float sL;
    int b = blockIdx.x, tid = threadIdx.x;
    if (tid < 64) {
        float m = partM[b * NTILES + tid];
        float l = partL[b * NTILES + tid];
        float M = m;
        #pragma unroll
        for (int off = 32; off; off >>= 1) M = fmaxf(M, __shfl_xor(M, off));
        float s = __expf(m - M);
        sc[tid] = s;
        float Lp = l * s;
        #pragma unroll
        for (int off = 32; off; off >>= 1) Lp += __shfl_xor(Lp, off);
        if (tid == 0) sL = Lp;
    }
    __syncthreads();
    float4 o = {0.f, 0.f, 0.f, 0.f};
    const float* base = partO + (size_t)b * NTILES * CTXD;
    #pragma unroll 4
    for (int i = 0; i < NTILES; ++i) {
        float s = sc[i];
        float4 p4 = *(const float4*)(base + (size_t)i * CTXD + tid * 4);
        o.x += s * p4.x; o.y += s * p4.y; o.z += s * p4.z; o.w += s * p4.w;
    }
    float inv = 1.0f / sL;
    float4 r; r.x = o.x * inv; r.y = o.y * inv; r.z = o.z * inv; r.w = o.w * inv;
    ((float4*)out)[b * (CTXD / 4) + tid] = r;
}

extern "C" void kernel_launch(void* const* d_in, const int* in_sizes, int n_in,
                              void* d_out, int out_size, void* d_ws, size_t ws_size,
                              hipStream_t stream) {
    const float* prev  = (const float*)d_in[2];   // [32,1,512]
    const float* enc   = (const float*)d_in[3];   // [32,4096,1024]
    const float* Ww    = (const float*)d_in[4];   // [256,512]
    const float* Wb    = (const float*)d_in[5];   // [256]
    const float* Uw    = (const float*)d_in[6];   // [256,1024]
    const float* Ubias = (const float*)d_in[7];   // [256]
    const float* v     = (const float*)d_in[8];   // [256]
    float* out = (float*)d_out;                   // [32,1024]

    char* ws = (char*)d_ws;
    float* bias          = (float*)ws;                          // 32 KB
    unsigned short* Ub   = (unsigned short*)(ws + 32768);       // 512 KB
    float* partO         = (float*)(ws + 32768 + 524288);       // 8 MB
    float* partM         = partO + (size_t)BB * NTILES * CTXD;  // 8 KB
    float* partL         = partM + BB * NTILES;                 // 8 KB

    hipFuncSetAttribute((const void*)attn_main,
                        hipFuncAttributeMaxDynamicSharedMemorySize, SMEM_BYTES);

    uconv_kernel<<<dim3(256), dim3(256), 0, stream>>>(Uw, Ub);
    bias_kernel<<<dim3(BB), dim3(HH), 0, stream>>>(prev, Ww, Wb, Ubias, bias);
    attn_main<<<dim3(BB * NTILES), dim3(256), SMEM_BYTES, stream>>>(enc, Ub, bias, v, partO, partM, partL);
    combine_kernel<<<dim3(BB), dim3(256), 0, stream>>>(partO, partM, partL, out);
}